// Round 6
// baseline (670.204 us; speedup 1.0000x reference)
//
#include <hip/hip_runtime.h>

#define NVOX 400000
#define K27 27
#define EPS_ 1e-5f

typedef short short8 __attribute__((ext_vector_type(8)));
typedef float floatx4 __attribute__((ext_vector_type(4)));
typedef unsigned int uintx4 __attribute__((ext_vector_type(4)));

// round-to-nearest-even fp32 -> bf16, packed pair (a low 16, b high 16)
__device__ __forceinline__ unsigned int pack2bf(float a, float b) {
    unsigned int ua = __builtin_bit_cast(unsigned int, a);
    unsigned int ub = __builtin_bit_cast(unsigned int, b);
    ua += 0x7fffu + ((ua >> 16) & 1u);
    ub += 0x7fffu + ((ub >> 16) & 1u);
    return (ua >> 16) | (ub & 0xffff0000u);
}

// async 16B global->LDS (direct, no VGPR round-trip).
// global source is PER-LANE; LDS dest is wave-uniform base + lane*16.
__device__ __forceinline__ void gload_lds16(const void* g, void* l) {
    __builtin_amdgcn_global_load_lds(
        (const __attribute__((address_space(1))) void*)g,
        (__attribute__((address_space(3))) void*)l, 16, 0, 0);
}

// blocks [0, fb): fp32->bf16 feature conversion (32 elems/thread)
// blocks [fb, fb+32): W[k][ci][co] -> wt[k][co][ci] bf16
// block  fb+32: zero the 128 stats accumulators + the zero-row
__global__ void prep_kernel(const float* __restrict__ w,
                            const float* __restrict__ feat,
                            unsigned short* __restrict__ feat_bf,
                            unsigned short* __restrict__ wt,
                            float* __restrict__ sums,
                            float* __restrict__ zrow,
                            int fb) {
    const int b = blockIdx.x;
    const int t = threadIdx.x;
    if (b < fb) {
#pragma unroll
        for (int r = 0; r < 4; ++r) {
            const int i0 = b * 8192 + r * 2048 + t * 8;
            const floatx4* s = (const floatx4*)(feat + i0);
            const floatx4 f0 = s[0], f1 = s[1];
            uintx4 v;
            v[0] = pack2bf(f0[0], f0[1]); v[1] = pack2bf(f0[2], f0[3]);
            v[2] = pack2bf(f1[0], f1[1]); v[3] = pack2bf(f1[2], f1[3]);
            *(uintx4*)(feat_bf + i0) = v;
        }
    } else if (b < fb + 32) {
        for (int g = (b - fb) * 256 + t; g < K27 * 64 * 64; g += 32 * 256) {
            const int k = g >> 12, r = g & 4095, co = r >> 6, ci = r & 63;
            unsigned int u =
                __builtin_bit_cast(unsigned int, w[(k << 12) + (ci << 6) + co]);
            u += 0x7fffu + ((u >> 16) & 1u);
            wt[g] = (unsigned short)(u >> 16);
        }
    } else {
        if (t < 128) sums[t] = 0.0f;
        else if (zrow && t < 136) zrow[t - 128] = 0.0f;
    }
}

// 128 rows x 64 out-ch per block (3125 blocks), 4 waves. Each wave OWNS its
// 32 rows end-to-end: wave tile M=32 x N=64 -> 2x4 mfma_f32_16x16x32_bf16
// per kb (acc 32 AGPR).
//
// R12: WAVE-PRIVATE depth-2 pipelines -- zero barriers in the k-loop.
// (R11 post-mortem: T_step GREW with stream count -> streams queue on the
// serial per-step chain; __syncthreads' vmcnt(0) drain caps prefetch slack
// at one COMPUTE regardless of buffering. R9/R10's cross-wave counted-vmcnt
// failed correctness twice; but vmcnt is PER-WAVE state -- wave-private
// counting over a homogeneous gload_lds stream is exactly the regime the
// proven patterns (m97/m135/m201) validated.)
//  * Each wave stages its own 4KB A-tile (rows wv*32..wv*32+31) into a
//    private LDS region via 4 gload_lds16 per k. No other wave touches it
//    -> no barrier, no cross-wave visibility reasoning. Depth-2: at step k
//    issue tile k+2 (4 ops), then s_waitcnt vmcnt(8) retires tile k
//    (outstanding <= 12, oldest 4 = tile k; per-wave in-order stream).
//  * Dummy tail stages (k+2 > 26) go to a scratch 4th buffer with tile-26
//    data: every step issues exactly 4 ops, wait literal uniform.
//  * B fragments: compiler-managed global loads (16 contiguous bytes,
//    wt[k][nt*16+m][kb*32+q*8..]; 216KB total, L1/L2-resident). All 8
//    issue before the 16 MFMAs -> one exposed latency per step, hidden by
//    8 free-running waves/CU that never lockstep.
//  * idx preamble in LDS (one coalesced load + single __syncthreads before
//    the loop): per-step idx access is a ds_read broadcast.
//  * XOR chunk swizzle on the per-lane GLOBAL source + linear LDS dest
//    (g21); read side XORs the same way (R8-proven, zero conflicts).
//  * LDS 4x4x4KB + 13.5KB idx ~ 78KB -> 2 blocks/CU (8 waves).
template <bool BF16FEAT>
__launch_bounds__(256)
__global__ void conv_mfma(const float* __restrict__ feat,
                          const unsigned short* __restrict__ feat_bf,
                          const int* __restrict__ nmap,
                          const unsigned short* __restrict__ wt,
                          const unsigned short* __restrict__ zrow,
                          float* __restrict__ out,
                          float* __restrict__ sums) {
    // [wave][buffer 0..2 rotating + 3 dummy][32 rows x 64 ch]
    __shared__ __align__(16) unsigned short a_tile[4][4][32 * 64];  // 64 KB
    __shared__ int idx_lds[K27 * 128];                              // 13.5 KB
    __shared__ float cstat[128];

    const int tid  = threadIdx.x;
    const int wv   = tid >> 6;
    const int lane = tid & 63;
    const int m    = lane & 15;
    const int q    = lane >> 4;

    // bijective XCD-chunked remap (m204): each XCD gets a contiguous range
    const int nwg = gridDim.x;
    const int q8 = nwg >> 3, r8 = nwg & 7;
    const int xcd = blockIdx.x & 7, lin = blockIdx.x >> 3;
    const int wg =
        (xcd < r8 ? xcd * (q8 + 1) : r8 * (q8 + 1) + (xcd - r8) * q8) + lin;
    const int base = wg * 128;

    // ---- preamble: cache nmap[k][base..base+128) in LDS (coalesced)
    for (int j = tid; j < K27 * 128; j += 256)
        idx_lds[j] = nmap[(size_t)(j >> 7) * NVOX + base + (j & 127)];
    if (tid < 128) cstat[tid] = 0.0f;
    __syncthreads();  // the ONLY barrier before the epilogue

    // wave-private staging geometry: instr j covers wave-local rows
    // [j*8, j*8+8), 8 lanes per row: row = j*8 + (lane>>3), slot = lane&7.
    // Since row%8 == lane>>3, the global-source XOR swizzle
    // gcx = (lane&7) ^ (lane>>3) is j-independent. Slot (row,s) then holds
    // source chunk s ^ (row&7); the read side XORs the same way.
    const int rsub = lane >> 3;
    const int gcx  = (lane & 7) ^ rsub;

    floatx4 acc[2][4];
#pragma unroll
    for (int mt = 0; mt < 2; ++mt)
#pragma unroll
        for (int nt = 0; nt < 4; ++nt)
            acc[mt][nt] = (floatx4){0.f, 0.f, 0.f, 0.f};

// stage tile kk into this wave's buffer bufidx: exactly 4 gload_lds16.
// Inactive rows pull 16B from the zero-row (content irrelevant: zeros).
#define STAGE_A(bufidx, kk)                                                   \
    do {                                                                      \
        _Pragma("unroll") for (int j = 0; j < 4; ++j) {                       \
            const int ix = idx_lds[(kk) * 128 + wv * 32 + j * 8 + rsub];      \
            const unsigned short* src =                                       \
                (ix >= 0) ? feat_bf + (size_t)ix * 64 + gcx * 8 : zrow;       \
            gload_lds16(src, a_tile[wv][bufidx] + j * 512);                   \
        }                                                                     \
    } while (0)

// compute tile kk from this wave's buffer bufidx; B fragments direct from
// global (16 contiguous bytes each; all 8 issued before the MFMAs).
#define COMPUTE(bufidx, kk)                                                   \
    do {                                                                      \
        const unsigned short* bp = wt + (size_t)(kk) * 4096 + m * 64 + q * 8; \
        short8 b0[4], b1[4], a0[2], a1[2];                                    \
        _Pragma("unroll") for (int nt = 0; nt < 4; ++nt) {                    \
            b0[nt] = *(const short8*)(bp + nt * 1024);                        \
            b1[nt] = *(const short8*)(bp + nt * 1024 + 32);                   \
        }                                                                     \
        _Pragma("unroll") for (int mt = 0; mt < 2; ++mt) {                    \
            const int rl = mt * 16 + m;                                       \
            a0[mt] = *(const short8*)(                                        \
                a_tile[wv][bufidx] + (rl * 8 + (q ^ (rl & 7))) * 8);          \
            a1[mt] = *(const short8*)(                                        \
                a_tile[wv][bufidx] + (rl * 8 + ((4 + q) ^ (rl & 7))) * 8);    \
        }                                                                     \
        _Pragma("unroll") for (int mt = 0; mt < 2; ++mt)                      \
            _Pragma("unroll") for (int nt = 0; nt < 4; ++nt)                  \
                acc[mt][nt] = __builtin_amdgcn_mfma_f32_16x16x32_bf16(        \
                    a0[mt], b0[nt], acc[mt][nt], 0, 0, 0);                    \
        _Pragma("unroll") for (int mt = 0; mt < 2; ++mt)                      \
            _Pragma("unroll") for (int nt = 0; nt < 4; ++nt)                  \
                acc[mt][nt] = __builtin_amdgcn_mfma_f32_16x16x32_bf16(        \
                    a1[mt], b1[nt], acc[mt][nt], 0, 0, 0);                    \
    } while (0)

// step: issue tile kk+2 (into buf (kk+2)%3, or dummy buf 3 with tile-26
// data past the end -- always 4 ops), wait own vmcnt(8) (retires tile kk:
// outstanding <= 12, oldest 4 are tile kk's), compute tile kk.
#define STEP(bufC, bufS, kk)                                                  \
    do {                                                                      \
        const int t2 = (kk) + 2;                                              \
        if (t2 <= 26) STAGE_A(bufS, t2);                                      \
        else          STAGE_A(3, 26);                                         \
        asm volatile("s_waitcnt vmcnt(8)" ::: "memory");                      \
        COMPUTE(bufC, kk);                                                    \
    } while (0)

    if constexpr (BF16FEAT) {
        STAGE_A(0, 0);
        STAGE_A(1, 1);
        for (int kg = 0; kg < K27; kg += 3) {
            STEP(0, 2, kg);
            STEP(1, 0, kg + 1);
            STEP(2, 1, kg + 2);
        }
    } else {
        // fallback: fp32 gather + in-register pack, wave-private synchronous
        // (ds_write -> ds_read same wave; compiler orders via lgkmcnt)
        for (int kk = 0; kk < K27; ++kk) {
            short8 areg[4];
#pragma unroll
            for (int j = 0; j < 4; ++j) {
                const int ix = idx_lds[kk * 128 + wv * 32 + j * 8 + rsub];
                areg[j] = (short8){0, 0, 0, 0, 0, 0, 0, 0};
                if (ix >= 0) {
                    const float* fp = feat + (size_t)ix * 64 + gcx * 8;
                    const floatx4 f0 = *(const floatx4*)fp;
                    const floatx4 f1 = *(const floatx4*)(fp + 4);
                    uintx4 v;
                    v[0] = pack2bf(f0[0], f0[1]); v[1] = pack2bf(f0[2], f0[3]);
                    v[2] = pack2bf(f1[0], f1[1]); v[3] = pack2bf(f1[2], f1[3]);
                    areg[j] = __builtin_bit_cast(short8, v);
                }
            }
#pragma unroll
            for (int j = 0; j < 4; ++j)
                *(short8*)(a_tile[wv][0] +
                           ((j * 8 + rsub) * 8 + (lane & 7)) * 8) = areg[j];
            COMPUTE(0, kk);
        }
    }
#undef STEP
#undef STAGE_A
#undef COMPUTE

    // epilogue: store (C/D: col=lane&15, row=q*4+reg — m89-verified) + stats
#pragma unroll
    for (int nt = 0; nt < 4; ++nt) {
        const int col = nt * 16 + m;
        float s = 0.f, s2 = 0.f;
#pragma unroll
        for (int mt = 0; mt < 2; ++mt) {
            const int row0 = base + wv * 32 + mt * 16 + q * 4;
#pragma unroll
            for (int i = 0; i < 4; ++i) {
                const float v = acc[mt][nt][i];
                s += v;
                s2 += v * v;
                out[(size_t)(row0 + i) * 64 + col] = v;
            }
        }
        atomicAdd(&cstat[col], s);
        atomicAdd(&cstat[64 + col], s2);
    }
    __syncthreads();
    if (tid < 128) atomicAdd(&sums[tid], cstat[tid]);
}

__global__ void bn_apply(float* __restrict__ out, const float* __restrict__ sums,
                         const float* __restrict__ gamma,
                         const float* __restrict__ beta) {
    __shared__ float sc[64];
    __shared__ float sh[64];
    const int tid = threadIdx.x;
    if (tid < 64) {
        const float inv_n = 1.0f / (float)NVOX;
        const float mean = sums[tid] * inv_n;
        const float var  = sums[64 + tid] * inv_n - mean * mean;
        const float g    = gamma[tid] * rsqrtf(var + EPS_);
        sc[tid] = g;
        sh[tid] = beta[tid] - mean * g;
    }
    __syncthreads();
    const int cg = (tid & 15) * 4;
    floatx4 scale, shift;
#pragma unroll
    for (int j = 0; j < 4; ++j) {
        scale[j] = sc[cg + j];
        shift[j] = sh[cg + j];
    }
    floatx4* p = (floatx4*)out;
    const int total4 = NVOX * 16;
    for (int i = blockIdx.x * 256 + tid; i < total4; i += gridDim.x * 256) {
        floatx4 v = p[i] * scale + shift;
#pragma unroll
        for (int j = 0; j < 4; ++j) v[j] = v[j] > 0.f ? v[j] : 0.f;
        p[i] = v;
    }
}

extern "C" void kernel_launch(void* const* d_in, const int* in_sizes, int n_in,
                              void* d_out, int out_size, void* d_ws, size_t ws_size,
                              hipStream_t stream) {
    const float* feat  = (const float*)d_in[0];
    const int*   nmap  = (const int*)d_in[1];
    const float* w     = (const float*)d_in[2];
    const float* gamma = (const float*)d_in[3];
    const float* beta  = (const float*)d_in[4];
    float* out = (float*)d_out;

    const size_t FEATB = (size_t)NVOX * 64 * 2;      // 51,200,000
    const size_t WTB   = (size_t)K27 * 64 * 64 * 2;  //    221,184
    const int conv_blocks = NVOX / 128;              // 3125 exactly

    if (ws_size >= FEATB + WTB + 512 + 128) {
        unsigned short* feat_bf = (unsigned short*)d_ws;
        unsigned short* wt      = (unsigned short*)((char*)d_ws + FEATB);
        float* sums             = (float*)((char*)d_ws + FEATB + WTB);
        float* zrow             = (float*)((char*)d_ws + FEATB + WTB + 512);
        prep_kernel<<<dim3(3158), dim3(256), 0, stream>>>(
            w, feat, feat_bf, wt, sums, zrow, 3125);
        conv_mfma<true><<<dim3(conv_blocks), dim3(256), 0, stream>>>(
            feat, feat_bf, nmap, wt, (const unsigned short*)zrow, out, sums);
        bn_apply<<<dim3(1024), dim3(256), 0, stream>>>(out, sums, gamma, beta);
    } else {
        // fallback: fp32 gather + in-register pack (no feature buffer)
        unsigned short* wt = (unsigned short*)d_ws;
        float* sums        = (float*)((char*)d_ws + WTB);
        prep_kernel<<<dim3(33), dim3(256), 0, stream>>>(
            w, feat, nullptr, wt, sums, nullptr, 0);
        conv_mfma<false><<<dim3(conv_blocks), dim3(256), 0, stream>>>(
            feat, nullptr, nmap, wt, nullptr, out, sums);
        bn_apply<<<dim3(1024), dim3(256), 0, stream>>>(out, sums, gamma, beta);
    }
}

// Round 7
// 391.110 us; speedup vs baseline: 1.7136x; 1.7136x over previous
//
#include <hip/hip_runtime.h>

#define NVOX 400000
#define K27 27
#define EPS_ 1e-5f

typedef short short8 __attribute__((ext_vector_type(8)));
typedef float floatx4 __attribute__((ext_vector_type(4)));
typedef unsigned int uintx4 __attribute__((ext_vector_type(4)));

// round-to-nearest-even fp32 -> bf16, packed pair (a low 16, b high 16)
__device__ __forceinline__ unsigned int pack2bf(float a, float b) {
    unsigned int ua = __builtin_bit_cast(unsigned int, a);
    unsigned int ub = __builtin_bit_cast(unsigned int, b);
    ua += 0x7fffu + ((ua >> 16) & 1u);
    ub += 0x7fffu + ((ub >> 16) & 1u);
    return (ua >> 16) | (ub & 0xffff0000u);
}

// async 16B global->LDS (direct, no VGPR round-trip).
// global source is PER-LANE; LDS dest is wave-uniform base + lane*16.
__device__ __forceinline__ void gload_lds16(const void* g, void* l) {
    __builtin_amdgcn_global_load_lds(
        (const __attribute__((address_space(1))) void*)g,
        (__attribute__((address_space(3))) void*)l, 16, 0, 0);
}

// blocks [0, fb): fp32->bf16 feature conversion (32 elems/thread)
// blocks [fb, fb+32): W[k][ci][co] -> wt[k][co][ci] bf16
// block  fb+32: zero the 128 stats accumulators + the zero-row
__global__ void prep_kernel(const float* __restrict__ w,
                            const float* __restrict__ feat,
                            unsigned short* __restrict__ feat_bf,
                            unsigned short* __restrict__ wt,
                            float* __restrict__ sums,
                            float* __restrict__ zrow,
                            int fb) {
    const int b = blockIdx.x;
    const int t = threadIdx.x;
    if (b < fb) {
#pragma unroll
        for (int r = 0; r < 4; ++r) {
            const int i0 = b * 8192 + r * 2048 + t * 8;
            const floatx4* s = (const floatx4*)(feat + i0);
            const floatx4 f0 = s[0], f1 = s[1];
            uintx4 v;
            v[0] = pack2bf(f0[0], f0[1]); v[1] = pack2bf(f0[2], f0[3]);
            v[2] = pack2bf(f1[0], f1[1]); v[3] = pack2bf(f1[2], f1[3]);
            *(uintx4*)(feat_bf + i0) = v;
        }
    } else if (b < fb + 32) {
        for (int g = (b - fb) * 256 + t; g < K27 * 64 * 64; g += 32 * 256) {
            const int k = g >> 12, r = g & 4095, co = r >> 6, ci = r & 63;
            unsigned int u =
                __builtin_bit_cast(unsigned int, w[(k << 12) + (ci << 6) + co]);
            u += 0x7fffu + ((u >> 16) & 1u);
            wt[g] = (unsigned short)(u >> 16);
        }
    } else {
        if (t < 128) sums[t] = 0.0f;
        else if (zrow && t < 136) zrow[t - 128] = 0.0f;
    }
}

// 128 rows x 64 out-ch per block (3125 blocks). 4 waves, wave tile M=32 x
// N=64 -> 2x4 mfma_f32_16x16x32_bf16 per kb (acc 32 AGPR).
//
// R13 = R8 (best verified: 237us, __syncthreads-drained double buffer,
// gload_lds staging for A AND B) + 3-slot LDS idx window.
// (R7/R11/R12 post-mortem: B-from-global is a stride-128B gather = 64
// cache lines per instruction -- every such kernel was ~2x slower; B must
// stay in LDS. R8's remaining T_step ~1724cy carries ~600-900cy of nmap
// load latency at the HEAD of each step's chain: nmap value -> gather
// addresses, serial. R9/R10's counted-vmcnt failed correctness twice --
// likely ds_reads hoisted above the non-fencing raw s_barrier.)
//  * idx window: wave-0 lanes 0-31 gload_lds the 128 indices of tile k+3
//    into slot (k+3)%3 each step (ONE extra vmem instr/step). Stage of
//    tile k+1 reads indices from slot (k+1)%3 via ds_read broadcast
//    (~120cy) -- nmap latency leaves the serial chain. Visibility is by
//    the existing per-step __syncthreads (full fence + vmcnt drain): slot
//    t%3 written step t-3, read step t-1, overwritten step t. No counted
//    vmcnt anywhere.
//  * k-loop fully unrolled: all buffer/slot indices compile-time.
//  * everything else byte-identical to R8 (stage geometry, XOR source
//    swizzle + linear LDS dest, zero-row for inactive, COMPUTE reads,
//    epilogue).
template <bool BF16FEAT>
__launch_bounds__(256)
__global__ void conv_mfma(const float* __restrict__ feat,
                          const unsigned short* __restrict__ feat_bf,
                          const int* __restrict__ nmap,
                          const unsigned short* __restrict__ wt,
                          const unsigned short* __restrict__ zrow,
                          float* __restrict__ out,
                          float* __restrict__ sums) {
    __shared__ __align__(16) unsigned short a_tile[2][128 * 64];  // 2x16 KB
    __shared__ __align__(16) unsigned short b_tile[2][64 * 64];   // 2x 8 KB
    __shared__ __align__(16) int idx_w[3 * 128];                  // 1.5 KB
    __shared__ float cstat[128];

    const int tid  = threadIdx.x;
    const int wv   = tid >> 6;
    const int lane = tid & 63;
    const int m    = lane & 15;
    const int q    = lane >> 4;

    // bijective XCD-chunked remap (m204): each XCD gets a contiguous range
    const int nwg = gridDim.x;
    const int q8 = nwg >> 3, r8 = nwg & 7;
    const int xcd = blockIdx.x & 7, lin = blockIdx.x >> 3;
    const int wg =
        (xcd < r8 ? xcd * (q8 + 1) : r8 * (q8 + 1) + (xcd - r8) * q8) + lin;
    const int base = wg * 128;

    if (tid < 128) cstat[tid] = 0.0f;

    // staging geometry (R8-proven): A chunk j -> row (j*4+wv)*8+(lane>>3),
    // slot-col lane&7; row%8 == lane>>3 so the global-source XOR swizzle
    // gcx = (lane&7) ^ (lane>>3) is j-independent. Slot (row,s) holds
    // source chunk s ^ (row&7); the read side XORs the same way.
    const int rsub = lane >> 3;
    const int gcx  = (lane & 7) ^ rsub;
    int arow[4];
#pragma unroll
    for (int j = 0; j < 4; ++j) arow[j] = (j * 4 + wv) * 8 + rsub;

    int row_a[2];
#pragma unroll
    for (int mt = 0; mt < 2; ++mt) row_a[mt] = wv * 32 + mt * 16 + m;

    floatx4 acc[2][4];
#pragma unroll
    for (int mt = 0; mt < 2; ++mt)
#pragma unroll
        for (int nt = 0; nt < 4; ++nt)
            acc[mt][nt] = (floatx4){0.f, 0.f, 0.f, 0.f};

#define COMPUTE(bufidx, kk)                                                   \
    do {                                                                      \
        _Pragma("unroll") for (int kb = 0; kb < 2; ++kb) {                    \
            short8 af[2], bfr[4];                                             \
            _Pragma("unroll") for (int mt = 0; mt < 2; ++mt)                  \
                af[mt] = *(const short8*)(                                    \
                    a_tile[bufidx] +                                          \
                    (row_a[mt] * 8 + ((kb * 4 + q) ^ (row_a[mt] & 7))) * 8);  \
            _Pragma("unroll") for (int nt = 0; nt < 4; ++nt) {                \
                const int row = nt * 16 + m;                                  \
                bfr[nt] = *(const short8*)(                                   \
                    b_tile[bufidx] +                                          \
                    (row * 8 + ((kb * 4 + q) ^ (row & 7))) * 8);              \
            }                                                                 \
            _Pragma("unroll") for (int mt = 0; mt < 2; ++mt)                  \
                _Pragma("unroll") for (int nt = 0; nt < 4; ++nt)              \
                    acc[mt][nt] = __builtin_amdgcn_mfma_f32_16x16x32_bf16(    \
                        af[mt], bfr[nt], acc[mt][nt], 0, 0, 0);               \
        }                                                                     \
    } while (0)

    if constexpr (BF16FEAT) {
// stage tile t into buffers bufidx. B first (no dependency), then the
// idx-dependent A gathers (idx from window slot rs via ds_read broadcast).
#define STAGE(bufidx, t, rs)                                                  \
    do {                                                                      \
        _Pragma("unroll") for (int j = 0; j < 2; ++j) {                       \
            const int brw = (j * 4 + wv) * 8 + rsub;                          \
            gload_lds16(wt + (size_t)(t) * 4096 + brw * 64 + gcx * 8,         \
                        b_tile[bufidx] + (j * 4 + wv) * 512);                 \
        }                                                                     \
        int ixr[4];                                                           \
        _Pragma("unroll") for (int j = 0; j < 4; ++j)                         \
            ixr[j] = idx_w[(rs) * 128 + arow[j]];                             \
        _Pragma("unroll") for (int j = 0; j < 4; ++j) {                       \
            const unsigned short* src =                                       \
                (ixr[j] >= 0) ? feat_bf + (size_t)ixr[j] * 64 + gcx * 8       \
                              : zrow;                                         \
            gload_lds16(src, a_tile[bufidx] + (j * 4 + wv) * 512);            \
        }                                                                     \
    } while (0)

// wave-0 lanes 0-31: pull 128 indices of tile t into window slot t%3
#define GIDX(t)                                                               \
    do {                                                                      \
        if (tid < 32)                                                         \
            gload_lds16(nmap + (size_t)(t) * NVOX + base + tid * 4,           \
                        idx_w + ((t) % 3) * 128);                             \
    } while (0)

        // ---- prologue: tile-0 idx via direct VGPR loads; window slots for
        //      tiles 1,2; stage tile 0; drain everything (clean baseline).
        GIDX(1);
        GIDX(2);
        {
            int i0[4];
#pragma unroll
            for (int j = 0; j < 4; ++j)
                i0[j] = nmap[(size_t)0 * NVOX + base + arow[j]];
#pragma unroll
            for (int j = 0; j < 2; ++j) {
                const int brw = (j * 4 + wv) * 8 + rsub;
                gload_lds16(wt + brw * 64 + gcx * 8,
                            b_tile[0] + (j * 4 + wv) * 512);
            }
#pragma unroll
            for (int j = 0; j < 4; ++j) {
                const unsigned short* src =
                    (i0[j] >= 0) ? feat_bf + (size_t)i0[j] * 64 + gcx * 8
                                 : zrow;
                gload_lds16(src, a_tile[0] + (j * 4 + wv) * 512);
            }
        }
        __syncthreads();  // tile 0 + idx slots 1,2 resident; vmcnt drained

        // ---- 27 steps, fully unrolled (all buf/slot indices constant).
        // step kk: stage tile kk+1 (buf kk+1&1, idx slot (kk+1)%3), gather
        // idx of tile kk+3 into slot (kk+3)%3, compute tile kk, barrier.
#pragma unroll
        for (int kk = 0; kk < K27; ++kk) {
            const int bufC = kk & 1;
            if (kk + 1 < K27) STAGE(bufC ^ 1, kk + 1, (kk + 1) % 3);
            if (kk + 3 < K27) GIDX(kk + 3);
            COMPUTE(bufC, kk);
            __syncthreads();  // drains stage+idx; all reads of bufC done
        }
#undef GIDX
#undef STAGE
    } else {
        // fallback: fp32 gather + in-register pack, single-buffered staging
        for (int kk = 0; kk < K27; ++kk) {
            short8 areg[4], breg[2];
            int farow[4];
#pragma unroll
            for (int j = 0; j < 4; ++j) {
                const int c = tid + 256 * j;
                farow[j] = c >> 3;
                const int gcs = c & 7;
                const int ix = nmap[(size_t)kk * NVOX + base + farow[j]];
                areg[j] = (short8){0, 0, 0, 0, 0, 0, 0, 0};
                if (ix >= 0) {
                    const float* fp = feat + (size_t)ix * 64 + gcs * 8;
                    const floatx4 f0 = *(const floatx4*)fp;
                    const floatx4 f1 = *(const floatx4*)(fp + 4);
                    uintx4 v;
                    v[0] = pack2bf(f0[0], f0[1]); v[1] = pack2bf(f0[2], f0[3]);
                    v[2] = pack2bf(f1[0], f1[1]); v[3] = pack2bf(f1[2], f1[3]);
                    areg[j] = __builtin_bit_cast(short8, v);
                }
            }
#pragma unroll
            for (int j = 0; j < 2; ++j) {
                const int c = tid + 256 * j;
                breg[j] = *(const short8*)(wt + kk * 4096 + c * 8);
            }
            __syncthreads();  // previous iter's reads done
#pragma unroll
            for (int j = 0; j < 4; ++j) {
                const int c = tid + 256 * j;
                *(short8*)(a_tile[0] +
                           (farow[j] * 8 + ((c & 7) ^ (farow[j] & 7))) * 8) =
                    areg[j];
            }
#pragma unroll
            for (int j = 0; j < 2; ++j) {
                const int c = tid + 256 * j;
                const int br = c >> 3;
                *(short8*)(b_tile[0] + (br * 8 + ((c & 7) ^ (br & 7))) * 8) =
                    breg[j];
            }
            __syncthreads();
            COMPUTE(0, kk);
        }
    }
#undef COMPUTE

    // epilogue: store (C/D: col=lane&15, row=q*4+reg — m89-verified) + stats
#pragma unroll
    for (int nt = 0; nt < 4; ++nt) {
        const int col = nt * 16 + m;
        float s = 0.f, s2 = 0.f;
#pragma unroll
        for (int mt = 0; mt < 2; ++mt) {
            const int row0 = base + wv * 32 + mt * 16 + q * 4;
#pragma unroll
            for (int i = 0; i < 4; ++i) {
                const float v = acc[mt][nt][i];
                s += v;
                s2 += v * v;
                out[(size_t)(row0 + i) * 64 + col] = v;
            }
        }
        atomicAdd(&cstat[col], s);
        atomicAdd(&cstat[64 + col], s2);
    }
    __syncthreads();
    if (tid < 128) atomicAdd(&sums[tid], cstat[tid]);
}

__global__ void bn_apply(float* __restrict__ out, const float* __restrict__ sums,
                         const float* __restrict__ gamma,
                         const float* __restrict__ beta) {
    __shared__ float sc[64];
    __shared__ float sh[64];
    const int tid = threadIdx.x;
    if (tid < 64) {
        const float inv_n = 1.0f / (float)NVOX;
        const float mean = sums[tid] * inv_n;
        const float var  = sums[64 + tid] * inv_n - mean * mean;
        const float g    = gamma[tid] * rsqrtf(var + EPS_);
        sc[tid] = g;
        sh[tid] = beta[tid] - mean * g;
    }
    __syncthreads();
    const int cg = (tid & 15) * 4;
    floatx4 scale, shift;
#pragma unroll
    for (int j = 0; j < 4; ++j) {
        scale[j] = sc[cg + j];
        shift[j] = sh[cg + j];
    }
    floatx4* p = (floatx4*)out;
    const int total4 = NVOX * 16;
    for (int i = blockIdx.x * 256 + tid; i < total4; i += gridDim.x * 256) {
        floatx4 v = p[i] * scale + shift;
#pragma unroll
        for (int j = 0; j < 4; ++j) v[j] = v[j] > 0.f ? v[j] : 0.f;
        p[i] = v;
    }
}

extern "C" void kernel_launch(void* const* d_in, const int* in_sizes, int n_in,
                              void* d_out, int out_size, void* d_ws, size_t ws_size,
                              hipStream_t stream) {
    const float* feat  = (const float*)d_in[0];
    const int*   nmap  = (const int*)d_in[1];
    const float* w     = (const float*)d_in[2];
    const float* gamma = (const float*)d_in[3];
    const float* beta  = (const float*)d_in[4];
    float* out = (float*)d_out;

    const size_t FEATB = (size_t)NVOX * 64 * 2;      // 51,200,000
    const size_t WTB   = (size_t)K27 * 64 * 64 * 2;  //    221,184
    const int conv_blocks = NVOX / 128;              // 3125 exactly

    if (ws_size >= FEATB + WTB + 512 + 128) {
        unsigned short* feat_bf = (unsigned short*)d_ws;
        unsigned short* wt      = (unsigned short*)((char*)d_ws + FEATB);
        float* sums             = (float*)((char*)d_ws + FEATB + WTB);
        float* zrow             = (float*)((char*)d_ws + FEATB + WTB + 512);
        prep_kernel<<<dim3(3158), dim3(256), 0, stream>>>(
            w, feat, feat_bf, wt, sums, zrow, 3125);
        conv_mfma<true><<<dim3(conv_blocks), dim3(256), 0, stream>>>(
            feat, feat_bf, nmap, wt, (const unsigned short*)zrow, out, sums);
        bn_apply<<<dim3(1024), dim3(256), 0, stream>>>(out, sums, gamma, beta);
    } else {
        // fallback: fp32 gather + in-register pack (no feature buffer)
        unsigned short* wt = (unsigned short*)d_ws;
        float* sums        = (float*)((char*)d_ws + WTB);
        prep_kernel<<<dim3(33), dim3(256), 0, stream>>>(
            w, feat, nullptr, wt, sums, nullptr, 0);
        conv_mfma<false><<<dim3(conv_blocks), dim3(256), 0, stream>>>(
            feat, nullptr, nmap, wt, nullptr, out, sums);
        bn_apply<<<dim3(1024), dim3(256), 0, stream>>>(out, sums, gamma, beta);
    }
}